// Round 13
// baseline (95.171 us; speedup 1.0000x reference)
//
#include <hip/hip_runtime.h>
#include <hip/hip_bf16.h>

// Problem constants
constexpr int NG = 16;    // experts
constexpr int ND = 512;   // feature dim
constexpr int NB = 4096;  // batch
constexpr int DD = ND * ND;

typedef __attribute__((ext_vector_type(8))) short short8;
typedef __attribute__((ext_vector_type(4))) short short4v;
typedef __attribute__((ext_vector_type(4))) float f32x4;

// ---------------- meta layout in d_ws (ints) ----------------
constexpr int OFFS   = 0;    // 17 ints: per-expert offsets + total
constexpr int TILEG  = 32;   // tile -> expert
constexpr int TILEM  = 112;  // tile -> m-tile within expert
constexpr int NTILES = 192;  // 1 int
constexpr int TLIST  = 256;  // 4096 ints: compact pos -> token

constexpr size_t META_BYTES = 32768;
constexpr size_t HC_OFF = META_BYTES;                    // bf16 [2][4096][512] = 8 MB
constexpr size_t FAST_WS_NEED = HC_OFF + 2ull * NB * ND * 2;

// legacy ws layout
constexpr size_t H_OFF = 32768;

__device__ inline unsigned short f2bf(float f) {          // RNE (legacy path)
  union { float f; unsigned u; } a; a.f = f;
  unsigned u = a.u;
  return (unsigned short)((u + 0x7fffu + ((u >> 16) & 1u)) >> 16);
}

__device__ inline short f2bf_hw(float f) {                // native cvt (RNE)
  __bf16 h = (__bf16)f;
  return __builtin_bit_cast(short, h);
}

__device__ inline float ftanh(float x) {
  float e = __expf(2.0f * x);
  return 1.0f - 2.0f * __builtin_amdgcn_rcpf(e + 1.0f);
}

__device__ inline void gld16(const void* g, void* lds) {
  __builtin_amdgcn_global_load_lds(
      (const __attribute__((address_space(1))) unsigned int*)g,
      (__attribute__((address_space(3))) unsigned int*)lds, 16, 0, 0);
}

__device__ inline unsigned lds_off(const void* p) {
  return (unsigned)(size_t)(const __attribute__((address_space(3))) char*)p;
}

#define DS128(d, a, OFF) \
  asm volatile("ds_read_b128 %0, %1 offset:%c2" : "=v"(d) : "v"(a), "i"(OFF) : "memory")
#define TRB16(d, a, OFF) \
  asm volatile("ds_read_b64_tr_b16 %0, %1 offset:%c2" : "=v"(d) : "v"(a), "i"(OFF) : "memory")

// ---------------- binning: ballot-based, atomic-light ----------------
__global__ void bin_k(const int* __restrict__ goal, int* __restrict__ meta, int tm) {
  __shared__ int cnt[NG], cur[NG];
  const int t = threadIdx.x;
  const int lane = t & 63;
  const int w = t >> 6;            // wave id 0..3
  if (t < NG) cnt[t] = 0;
  __syncthreads();

  // phase 1: ballot counting; one atomic per expert per wave
  int local[NG];
#pragma unroll
  for (int g = 0; g < NG; ++g) local[g] = 0;
  for (int base = w * 64; base < NB; base += 256) {
    const int gl = goal[base + lane];
#pragma unroll
    for (int g = 0; g < NG; ++g) {
      unsigned long long m = __ballot(gl == g);
      local[g] += (int)__popcll(m);
    }
  }
  if (lane == 0) {
#pragma unroll
    for (int g = 0; g < NG; ++g) atomicAdd(&cnt[g], local[g]);
  }
  __syncthreads();

  if (t == 0) {
    int s = 0, nt = 0;
    for (int g = 0; g < NG; ++g) {
      meta[OFFS + g] = s;
      cur[g] = s;
      int c = cnt[g];
      int mts = (c + tm - 1) / tm;
      for (int m = 0; m < mts; ++m) { meta[TILEG + nt] = g; meta[TILEM + nt] = m; ++nt; }
      s += c;
    }
    meta[OFFS + NG] = s;
    meta[NTILES] = nt;
  }
  __syncthreads();

  // phase 2: scatter; leader-lane atomic per (wave, chunk, expert)
  for (int base = w * 64; base < NB; base += 256) {
    const int tok = base + lane;
    const int gl = goal[tok];
#pragma unroll
    for (int g = 0; g < NG; ++g) {
      unsigned long long m = __ballot(gl == g);
      if (m) {
        const int c = (int)__popcll(m);
        const int leader = (int)__ffsll((unsigned long long)m) - 1;
        int b = 0;
        if (lane == leader) b = atomicAdd(&cur[g], c);
        b = __shfl(b, leader, 64);
        if (gl == g) {
          const int rank = (int)__popcll(m & ((1ULL << lane) - 1ULL));
          meta[TLIST + b + rank] = tok;
        }
      }
    }
  }
}

// ---------------- GEMM (round-8 proven): 128m x 64n tile, BK=64 ----------------
// MODE 0: A = features f32 gathered by token, reg-staged convert -> swizzled As.
//         Out: Hc bf16 (tanh).
// MODE 1: A = Hc bf16 compact via global_load_lds (pre-swizzled src, linear dest).
//         Out: f32 scatter to token rows (tanh).
// B: W f32 [k][n] -> coalesced row loads -> cvt -> subtiled LDS
//    (idx=(k>>2)*4+(n>>4), 128 B subtiles; within: (k&3)*32+(n&15)*2)
//    -> ds_read_b64_tr_b16 (col = addr bits[6:3]).
// XCD-chunked bijective block swizzle: 48 consecutive y-tiles per XCD chunk.
template<int MODE>
__global__ __launch_bounds__(256, 3) void gemm_t(
    const float* __restrict__ Xf,
    unsigned short* __restrict__ Hc,
    const float* __restrict__ Wp, const float* __restrict__ Wv,
    const float* __restrict__ bp, const float* __restrict__ bv,
    const int* __restrict__ meta,
    float* __restrict__ out)
{
  __shared__ __attribute__((aligned(128))) unsigned short As[2][128 * 64];
  __shared__ __attribute__((aligned(128))) unsigned short Bs[2][64 * 64];

  // ---- XCD-chunked bijective swizzle (NL = 8*48 = 384) ----
  const int orig = blockIdx.x + 8 * blockIdx.y;
  const int L    = (orig & 7) * 48 + (orig >> 3);
  const int nb   = L & 7;        // n-block
  const int tileIdx = L >> 3;    // y-tile

  if (tileIdx >= meta[NTILES]) return;
  const int g    = meta[TILEG + tileIdx];
  const int mt   = meta[TILEM + tileIdx];
  const int off  = meta[OFFS + g];
  const int cnt  = meta[OFFS + g + 1] - off;
  const int row0 = mt * 128;
  const int n0   = nb * 64;
  const int br   = blockIdx.z;

  const float* W    = (br ? Wv : Wp) + (size_t)g * DD;
  const float* bias = (br ? bv : bp) + (size_t)g * ND;

  const int t    = threadIdx.x;
  const int lane = t & 63;
  const int wid  = t >> 6;

  // ---- A staging geometry ----
  const int ao = t & 7;
  int tokA[4];
  const unsigned short* srcA[4];
  bool okA[4];
  const unsigned short* Ab = Hc + (size_t)(MODE == 1 ? br : 0) * NB * ND;

  if (MODE == 0) {
#pragma unroll
    for (int i = 0; i < 4; ++i) {
      int r = i * 32 + (t >> 3);
      tokA[i] = (row0 + r < cnt) ? meta[TLIST + off + row0 + r] : meta[TLIST + off];
    }
  } else {
#pragma unroll
    for (int c = 0; c < 4; ++c) {
      int o = c * 4096 + wid * 1024 + lane * 16;
      int r = o >> 7, w = o & 127;
      int so = (w ^ ((r & 7) << 4)) >> 1;
      okA[c]  = (row0 + r < cnt);
      srcA[c] = Ab + (size_t)(off + (okA[c] ? row0 + r : 0)) * ND + so;
    }
  }

  float rA[4][8];           // MODE 0 staging regs
  auto loadA0 = [&](int k0) {
#pragma unroll
    for (int i = 0; i < 4; ++i) {
      const float* p = Xf + (size_t)tokA[i] * ND + k0 + ao * 8;
      *reinterpret_cast<float4*>(&rA[i][0]) = *reinterpret_cast<const float4*>(p);
      *reinterpret_cast<float4*>(&rA[i][4]) = *reinterpret_cast<const float4*>(p + 4);
    }
  };
  auto writeA0 = [&](int buf) {
#pragma unroll
    for (int i = 0; i < 4; ++i) {
      const int r = i * 32 + (t >> 3);
      short8 o;
#pragma unroll
      for (int j = 0; j < 8; ++j) o[j] = f2bf_hw(rA[i][j]);
      *reinterpret_cast<short8*>(
          (char*)&As[buf][0] + r * 128 + ((ao * 16) ^ ((r & 7) << 4))) = o;
    }
  };
  auto loadA1 = [&](int buf, int k0) {
    char* dst = (char*)&As[buf][0];
#pragma unroll
    for (int c = 0; c < 4; ++c)
      if (okA[c]) gld16(srcA[c] + k0, dst + c * 4096 + wid * 1024);
  };

  // ---- B staging: thread covers rows kb, kb+32, cols co*8..+7 ----
  const int kb = t >> 3;    // 0..31
  const int co = t & 7;     // 0..7
  float rB[16];

  auto loadB = [&](int k0) {
#pragma unroll
    for (int h = 0; h < 2; ++h) {
      const float* p = W + (size_t)(k0 + kb + h * 32) * ND + n0 + co * 8;
      *reinterpret_cast<float4*>(&rB[h * 8])     = *reinterpret_cast<const float4*>(p);
      *reinterpret_cast<float4*>(&rB[h * 8 + 4]) = *reinterpret_cast<const float4*>(p + 4);
    }
  };
  auto writeB = [&](int buf) {
#pragma unroll
    for (int h = 0; h < 2; ++h) {
      const int k = kb + h * 32;
      short8 o;
#pragma unroll
      for (int j = 0; j < 8; ++j) o[j] = f2bf_hw(rB[h * 8 + j]);
      *reinterpret_cast<short8*>(
          (char*)&Bs[buf][0] + ((k >> 2) * 4 + (co >> 1)) * 128 + (k & 3) * 32 + (co & 1) * 16) = o;
    }
  };

  // ---- wave compute geometry ----
  const int wr  = (wid >> 1) * 64;
  const int wc  = (wid & 1) * 32;
  const int llo = lane & 15;
  const int lhi = lane >> 4;
  const int swz = (llo & 7) << 4;
  const unsigned c0 = (unsigned)((lhi * 16) ^ swz);
  const unsigned c1 = (unsigned)((64 + lhi * 16) ^ swz);
  const unsigned aAddr0 = lds_off(&As[0][0]) + (wr + llo) * 128;
  const unsigned bAddr0 = lds_off(&Bs[0][0]) + lhi * 1024 + (wc >> 4) * 128 + llo * 8;

  f32x4 acc[4][2];
#pragma unroll
  for (int i = 0; i < 4; ++i)
#pragma unroll
    for (int j = 0; j < 2; ++j) acc[i][j] = f32x4{0.f, 0.f, 0.f, 0.f};

  // prologue: fill buf 0
  if (MODE == 0) { loadA0(0); } else { loadA1(0, 0); }
  loadB(0);
  if (MODE == 0) writeA0(0);
  writeB(0);
  __syncthreads();

  for (int kt = 0; kt < 8; ++kt) {
    const int cb = kt & 1;
    const unsigned aOff = (unsigned)cb * 16384u;
    const unsigned bOff = (unsigned)cb * 8192u;
    if (kt < 7) {             // issue next-tile global loads early (T14)
      if (MODE == 0) { loadA0((kt + 1) * 64); } else { loadA1(cb ^ 1, (kt + 1) * 64); }
      loadB((kt + 1) * 64);
    }
#pragma unroll
    for (int kk = 0; kk < 2; ++kk) {
      const unsigned aA = aAddr0 + aOff + (kk ? c1 : c0);
      const unsigned bA = bAddr0 + bOff;
      short8 a0, a1, a2, a3;
      short4v t00, t01, t10, t11;
      DS128(a0, aA, 0);
      DS128(a1, aA, 2048);
      DS128(a2, aA, 4096);
      DS128(a3, aA, 6144);
      if (kk == 0) {
        TRB16(t00, bA, 0);    TRB16(t01, bA, 512);
        TRB16(t10, bA, 128);  TRB16(t11, bA, 640);
      } else {
        TRB16(t00, bA, 4096); TRB16(t01, bA, 4608);
        TRB16(t10, bA, 4224); TRB16(t11, bA, 4736);
      }
      asm volatile("s_waitcnt lgkmcnt(0)" ::: "memory");
      __builtin_amdgcn_sched_barrier(0);
      short8 b0 = __builtin_shufflevector(t00, t01, 0, 1, 2, 3, 4, 5, 6, 7);
      short8 b1 = __builtin_shufflevector(t10, t11, 0, 1, 2, 3, 4, 5, 6, 7);
      acc[0][0] = __builtin_amdgcn_mfma_f32_16x16x32_bf16(a0, b0, acc[0][0], 0, 0, 0);
      acc[0][1] = __builtin_amdgcn_mfma_f32_16x16x32_bf16(a0, b1, acc[0][1], 0, 0, 0);
      acc[1][0] = __builtin_amdgcn_mfma_f32_16x16x32_bf16(a1, b0, acc[1][0], 0, 0, 0);
      acc[1][1] = __builtin_amdgcn_mfma_f32_16x16x32_bf16(a1, b1, acc[1][1], 0, 0, 0);
      acc[2][0] = __builtin_amdgcn_mfma_f32_16x16x32_bf16(a2, b0, acc[2][0], 0, 0, 0);
      acc[2][1] = __builtin_amdgcn_mfma_f32_16x16x32_bf16(a2, b1, acc[2][1], 0, 0, 0);
      acc[3][0] = __builtin_amdgcn_mfma_f32_16x16x32_bf16(a3, b0, acc[3][0], 0, 0, 0);
      acc[3][1] = __builtin_amdgcn_mfma_f32_16x16x32_bf16(a3, b1, acc[3][1], 0, 0, 0);
    }
    if (kt < 7) {
      if (MODE == 0) writeA0(cb ^ 1);
      writeB(cb ^ 1);
      __syncthreads();
    }
  }

  // epilogue: bias + tanh + store
  float bj[2];
#pragma unroll
  for (int j = 0; j < 2; ++j) bj[j] = bias[n0 + wc + j * 16 + llo];

#pragma unroll
  for (int i = 0; i < 4; ++i) {
#pragma unroll
    for (int reg = 0; reg < 4; ++reg) {
      const int orow = wr + i * 16 + lhi * 4 + reg;
      if (row0 + orow < cnt) {
        if (MODE == 0) {
          size_t rb = (size_t)br * NB * ND + (size_t)(off + row0 + orow) * ND + n0;
#pragma unroll
          for (int j = 0; j < 2; ++j)
            Hc[rb + wc + j * 16 + llo] =
                (unsigned short)f2bf_hw(ftanh(acc[i][j][reg] + bj[j]));
        } else {
          const int tok = meta[TLIST + off + row0 + orow];
          size_t rb = (size_t)br * NB * ND + (size_t)tok * ND + n0;
#pragma unroll
          for (int j = 0; j < 2; ++j)
            out[rb + wc + j * 16 + llo] = ftanh(acc[i][j][reg] + bj[j]);
        }
      }
    }
  }
}

// ================= legacy fallback (round-2 proven, small ws) =================
constexpr int LTM = 64;
constexpr int LTN = 64;
constexpr int LBKT = 64;
constexpr int LBKP = LBKT + 8;
constexpr int LNT = ND / LTN;
constexpr int LMT_CAP = NB / LTM + NG;

template<int MODE>
__global__ __launch_bounds__(256, 4) void mlp_gemm(
    const float* __restrict__ X,
    __hip_bfloat16* __restrict__ Hp,
    __hip_bfloat16* __restrict__ Hv,
    const float* __restrict__ Wp, const float* __restrict__ bp,
    const float* __restrict__ Wv, const float* __restrict__ bv,
    const int* __restrict__ meta,
    float* __restrict__ out)
{
  const int tileIdx = blockIdx.y;
  if (tileIdx >= meta[NTILES]) return;
  const int g   = meta[TILEG + tileIdx];
  const int mt  = meta[TILEM + tileIdx];
  const int off = meta[OFFS + g];
  const int cnt = meta[OFFS + g + 1] - off;
  const int row0 = mt * LTM;
  const int n0 = blockIdx.x * LTN;
  const int br = blockIdx.z;

  const float* Wt   = (br ? Wv : Wp) + (size_t)g * DD;
  const float* bias = (br ? bv : bp) + (size_t)g * ND;

  __shared__ unsigned short As[2][LTM][LBKP];
  __shared__ unsigned short Bs[2][LTN][LBKP];

  const int t = threadIdx.x;
  const int r = t >> 2;
  const int q = t & 3;

  const int gr = row0 + r;
  const bool rowok = (gr < cnt);
  int tok = 0;
  if (MODE == 0) tok = rowok ? meta[TLIST + off + gr] : 0;
  const float* arow = X + (size_t)tok * ND;
  const __hip_bfloat16* Hin = br ? Hv : Hp;
  const unsigned short* hrow =
      (const unsigned short*)(Hin + (size_t)(off + (rowok ? gr : 0)) * ND);

  auto stage = [&](int buf, int k0) {
    if (MODE == 0) {
#pragma unroll
      for (int i = 0; i < 4; ++i) {
        int c = q * 16 + i * 4;
        float4 v = make_float4(0.f, 0.f, 0.f, 0.f);
        if (rowok) v = *reinterpret_cast<const float4*>(arow + k0 + c);
        ushort4 s;
        s.x = f2bf(v.x); s.y = f2bf(v.y); s.z = f2bf(v.z); s.w = f2bf(v.w);
        *reinterpret_cast<ushort4*>(&As[buf][r][c]) = s;
      }
    } else {
#pragma unroll
      for (int i = 0; i < 2; ++i) {
        int c = q * 16 + i * 8;
        int4 v = make_int4(0, 0, 0, 0);
        if (rowok) v = *reinterpret_cast<const int4*>(hrow + k0 + c);
        *reinterpret_cast<int4*>(&As[buf][r][c]) = v;
      }
    }
#pragma unroll
    for (int i = 0; i < 4; ++i) {
      int c = q * 16 + i * 4;
      float4 v = *reinterpret_cast<const float4*>(Wt + (size_t)(k0 + r) * ND + n0 + c);
      Bs[buf][c + 0][r] = f2bf(v.x);
      Bs[buf][c + 1][r] = f2bf(v.y);
      Bs[buf][c + 2][r] = f2bf(v.z);
      Bs[buf][c + 3][r] = f2bf(v.w);
    }
  };

  const int lane = t & 63;
  const int wid  = t >> 6;
  const int wr   = (wid >> 1) * 32;
  const int wc   = (wid & 1) * 32;
  const int lhi  = lane >> 4;
  const int llo  = lane & 15;

  f32x4 acc[2][2];
#pragma unroll
  for (int i = 0; i < 2; ++i)
#pragma unroll
    for (int j = 0; j < 2; ++j) acc[i][j] = f32x4{0.f, 0.f, 0.f, 0.f};

  stage(0, 0);
  __syncthreads();

  for (int kt = 0; kt < ND / LBKT; ++kt) {
    const int cb = kt & 1;
    if (kt + 1 < ND / LBKT) stage(cb ^ 1, (kt + 1) * LBKT);
#pragma unroll
    for (int kk = 0; kk < 2; ++kk) {
      int kbb = kk * 32 + lhi * 8;
      short8 a0 = *reinterpret_cast<const short8*>(&As[cb][wr + llo][kbb]);
      short8 a1 = *reinterpret_cast<const short8*>(&As[cb][wr + 16 + llo][kbb]);
      short8 b0 = *reinterpret_cast<const short8*>(&Bs[cb][wc + llo][kbb]);
      short8 b1 = *reinterpret_cast<const short8*>(&Bs[cb][wc + 16 + llo][kbb]);
      acc[0][0] = __builtin_amdgcn_mfma_f32_16x16x32_bf16(a0, b0, acc[0][0], 0, 0, 0);
      acc[0][1] = __builtin_amdgcn_mfma_f32_16x16x32_bf16(a0, b1, acc[0][1], 0, 0, 0);
      acc[1][0] = __builtin_amdgcn_mfma_f32_16x16x32_bf16(a1, b0, acc[1][0], 0, 0, 0);
      acc[1][1] = __builtin_amdgcn_mfma_f32_16x16x32_bf16(a1, b1, acc[1][1], 0, 0, 0);
    }
    __syncthreads();
  }

  float bj0 = bias[n0 + wc + llo];
  float bj1 = bias[n0 + wc + 16 + llo];
  __hip_bfloat16* Hout = br ? Hv : Hp;
#pragma unroll
  for (int i = 0; i < 2; ++i) {
#pragma unroll
    for (int reg = 0; reg < 4; ++reg) {
      int m = wr + i * 16 + lhi * 4 + reg;
      int grr = row0 + m;
      if (grr < cnt) {
        float v0 = ftanh(acc[i][0][reg] + bj0);
        float v1 = ftanh(acc[i][1][reg] + bj1);
        if (MODE == 0) {
          size_t rowbase = (size_t)(off + grr) * ND + n0;
          Hout[rowbase + wc + llo]      = __float2bfloat16(v0);
          Hout[rowbase + wc + 16 + llo] = __float2bfloat16(v1);
        } else {
          int tok2 = meta[TLIST + off + grr];
          size_t rowbase = (size_t)br * NB * ND + (size_t)tok2 * ND + n0;
          out[rowbase + wc + llo]      = v0;
          out[rowbase + wc + 16 + llo] = v1;
        }
      }
    }
  }
}

extern "C" void kernel_launch(void* const* d_in, const int* in_sizes, int n_in,
                              void* d_out, int out_size, void* d_ws, size_t ws_size,
                              hipStream_t stream) {
  const float* features = (const float*)d_in[0];
  const float* Wp0 = (const float*)d_in[1];
  const float* bp0 = (const float*)d_in[2];
  const float* Wp1 = (const float*)d_in[3];
  const float* bp1 = (const float*)d_in[4];
  const float* Wv0 = (const float*)d_in[5];
  const float* bv0 = (const float*)d_in[6];
  const float* Wv1 = (const float*)d_in[7];
  const float* bv1 = (const float*)d_in[8];
  const int* goal  = (const int*)d_in[9];
  float* out = (float*)d_out;
  int* meta = (int*)d_ws;

  if (ws_size >= FAST_WS_NEED) {
    unsigned short* Hc = (unsigned short*)((char*)d_ws + HC_OFF);

    bin_k<<<1, 256, 0, stream>>>(goal, meta, 128);

    dim3 grid(ND / 64, NB / 128 + NG, 2);
    gemm_t<0><<<grid, 256, 0, stream>>>(features, Hc, Wp0, Wv0, bp0, bv0, meta, out);
    gemm_t<1><<<grid, 256, 0, stream>>>(features, Hc, Wp1, Wv1, bp1, bv1, meta, out);
  } else {
    __hip_bfloat16* Hp = (__hip_bfloat16*)((char*)d_ws + H_OFF);
    __hip_bfloat16* Hv = Hp + (size_t)NB * ND;

    bin_k<<<1, 256, 0, stream>>>(goal, meta, LTM);
    dim3 grid(LNT, LMT_CAP, 2);
    mlp_gemm<0><<<grid, 256, 0, stream>>>(features, Hp, Hv, Wp0, bp0, Wv0, bv0, meta, out);
    mlp_gemm<1><<<grid, 256, 0, stream>>>(features, Hp, Hv, Wp1, bp1, Wv1, bv1, meta, out);
  }
}

// Round 17
// 51.031 us; speedup vs baseline: 1.8650x; 1.8650x over previous
//
#include <hip/hip_runtime.h>
#include <hip/hip_bf16.h>

// Problem constants
constexpr int NG = 16;    // experts
constexpr int ND = 512;   // feature dim
constexpr int NB = 4096;  // batch
constexpr int DD = ND * ND;

typedef __attribute__((ext_vector_type(8))) short short8;
typedef __attribute__((ext_vector_type(4))) short short4v;
typedef __attribute__((ext_vector_type(4))) float f32x4;

// ---------------- meta layout in d_ws (ints) ----------------
constexpr int OFFS   = 0;    // 17 ints: per-expert offsets + total
constexpr int TILEG  = 32;   // tile -> expert
constexpr int TILEM  = 112;  // tile -> m-tile within expert
constexpr int NTILES = 192;  // 1 int
constexpr int TLIST  = 256;  // 4096 ints: compact pos -> token

constexpr size_t META_BYTES = 32768;
constexpr size_t HC_OFF = META_BYTES;                    // bf16 [2][4096][512] = 8 MB
constexpr size_t FAST_WS_NEED = HC_OFF + 2ull * NB * ND * 2;

// legacy ws layout
constexpr size_t H_OFF = 32768;

__device__ inline unsigned short f2bf(float f) {          // RNE (legacy path)
  union { float f; unsigned u; } a; a.f = f;
  unsigned u = a.u;
  return (unsigned short)((u + 0x7fffu + ((u >> 16) & 1u)) >> 16);
}

__device__ inline short f2bf_hw(float f) {                // native cvt (RNE)
  __bf16 h = (__bf16)f;
  return __builtin_bit_cast(short, h);
}

__device__ inline float ftanh(float x) {
  float e = __expf(2.0f * x);
  return 1.0f - 2.0f * __builtin_amdgcn_rcpf(e + 1.0f);
}

__device__ inline void gld16(const void* g, void* lds) {
  __builtin_amdgcn_global_load_lds(
      (const __attribute__((address_space(1))) unsigned int*)g,
      (__attribute__((address_space(3))) unsigned int*)lds, 16, 0, 0);
}

__device__ inline unsigned lds_off(const void* p) {
  return (unsigned)(size_t)(const __attribute__((address_space(3))) char*)p;
}

#define DS128(d, a, OFF) \
  asm volatile("ds_read_b128 %0, %1 offset:%c2" : "=v"(d) : "v"(a), "i"(OFF) : "memory")
#define TRB16(d, a, OFF) \
  asm volatile("ds_read_b64_tr_b16 %0, %1 offset:%c2" : "=v"(d) : "v"(a), "i"(OFF) : "memory")

// ---------------- binning: 1024 threads, int4 reads, LDS atomics ----------------
__global__ __launch_bounds__(1024) void bin_k(const int* __restrict__ goal,
                                              int* __restrict__ meta, int tm) {
  __shared__ int cnt[NG], cur[NG];
  const int t = threadIdx.x;            // 0..1023; thread owns tokens 4t..4t+3
  if (t < NG) cnt[t] = 0;
  __syncthreads();

  const int4 gl = reinterpret_cast<const int4*>(goal)[t];
  atomicAdd(&cnt[gl.x], 1);
  atomicAdd(&cnt[gl.y], 1);
  atomicAdd(&cnt[gl.z], 1);
  atomicAdd(&cnt[gl.w], 1);
  __syncthreads();

  if (t == 0) {
    int s = 0, nt = 0;
    for (int g = 0; g < NG; ++g) {
      meta[OFFS + g] = s;
      cur[g] = s;
      int c = cnt[g];
      int mts = (c + tm - 1) / tm;
      for (int m = 0; m < mts; ++m) { meta[TILEG + nt] = g; meta[TILEM + nt] = m; ++nt; }
      s += c;
    }
    meta[OFFS + NG] = s;
    meta[NTILES] = nt;
  }
  __syncthreads();

  meta[TLIST + atomicAdd(&cur[gl.x], 1)] = 4 * t + 0;
  meta[TLIST + atomicAdd(&cur[gl.y], 1)] = 4 * t + 1;
  meta[TLIST + atomicAdd(&cur[gl.z], 1)] = 4 * t + 2;
  meta[TLIST + atomicAdd(&cur[gl.w], 1)] = 4 * t + 3;
}

// ---------------- GEMM (round-8 proven): 128m x 64n tile, BK=64 ----------------
// MODE 0: A = features f32 gathered by token, reg-staged convert -> swizzled As.
//         Out: Hc bf16 (tanh).
// MODE 1: A = Hc bf16 compact via global_load_lds (pre-swizzled src, linear dest).
//         Out: f32 scatter to token rows (tanh).
// B: W f32 [k][n] -> coalesced row loads -> cvt -> subtiled LDS
//    (idx=(k>>2)*4+(n>>4), 128 B subtiles; within: (k&3)*32+(n&15)*2)
//    -> ds_read_b64_tr_b16 (col = addr bits[6:3]).
// XCD-chunked bijective block swizzle: 48 consecutive y-tiles per XCD chunk.
template<int MODE>
__global__ __launch_bounds__(256, 3) void gemm_t(
    const float* __restrict__ Xf,
    unsigned short* __restrict__ Hc,
    const float* __restrict__ Wp, const float* __restrict__ Wv,
    const float* __restrict__ bp, const float* __restrict__ bv,
    const int* __restrict__ meta,
    float* __restrict__ out)
{
  __shared__ __attribute__((aligned(128))) unsigned short As[2][128 * 64];
  __shared__ __attribute__((aligned(128))) unsigned short Bs[2][64 * 64];

  // ---- XCD-chunked bijective swizzle (NL = 8*48 = 384) ----
  const int orig = blockIdx.x + 8 * blockIdx.y;
  const int L    = (orig & 7) * 48 + (orig >> 3);
  const int nb   = L & 7;        // n-block
  const int tileIdx = L >> 3;    // y-tile

  if (tileIdx >= meta[NTILES]) return;
  const int g    = meta[TILEG + tileIdx];
  const int mt   = meta[TILEM + tileIdx];
  const int off  = meta[OFFS + g];
  const int cnt  = meta[OFFS + g + 1] - off;
  const int row0 = mt * 128;
  const int n0   = nb * 64;
  const int br   = blockIdx.z;

  const float* W    = (br ? Wv : Wp) + (size_t)g * DD;
  const float* bias = (br ? bv : bp) + (size_t)g * ND;

  const int t    = threadIdx.x;
  const int lane = t & 63;
  const int wid  = t >> 6;

  // ---- A staging geometry ----
  const int ao = t & 7;
  int tokA[4];
  const unsigned short* srcA[4];
  bool okA[4];
  const unsigned short* Ab = Hc + (size_t)(MODE == 1 ? br : 0) * NB * ND;

  if (MODE == 0) {
#pragma unroll
    for (int i = 0; i < 4; ++i) {
      int r = i * 32 + (t >> 3);
      tokA[i] = (row0 + r < cnt) ? meta[TLIST + off + row0 + r] : meta[TLIST + off];
    }
  } else {
#pragma unroll
    for (int c = 0; c < 4; ++c) {
      int o = c * 4096 + wid * 1024 + lane * 16;
      int r = o >> 7, w = o & 127;
      int so = (w ^ ((r & 7) << 4)) >> 1;
      okA[c]  = (row0 + r < cnt);
      srcA[c] = Ab + (size_t)(off + (okA[c] ? row0 + r : 0)) * ND + so;
    }
  }

  float rA[4][8];           // MODE 0 staging regs
  auto loadA0 = [&](int k0) {
#pragma unroll
    for (int i = 0; i < 4; ++i) {
      const float* p = Xf + (size_t)tokA[i] * ND + k0 + ao * 8;
      *reinterpret_cast<float4*>(&rA[i][0]) = *reinterpret_cast<const float4*>(p);
      *reinterpret_cast<float4*>(&rA[i][4]) = *reinterpret_cast<const float4*>(p + 4);
    }
  };
  auto writeA0 = [&](int buf) {
#pragma unroll
    for (int i = 0; i < 4; ++i) {
      const int r = i * 32 + (t >> 3);
      short8 o;
#pragma unroll
      for (int j = 0; j < 8; ++j) o[j] = f2bf_hw(rA[i][j]);
      *reinterpret_cast<short8*>(
          (char*)&As[buf][0] + r * 128 + ((ao * 16) ^ ((r & 7) << 4))) = o;
    }
  };
  auto loadA1 = [&](int buf, int k0) {
    char* dst = (char*)&As[buf][0];
#pragma unroll
    for (int c = 0; c < 4; ++c)
      if (okA[c]) gld16(srcA[c] + k0, dst + c * 4096 + wid * 1024);
  };

  // ---- B staging: thread covers rows kb, kb+32, cols co*8..+7 ----
  const int kb = t >> 3;    // 0..31
  const int co = t & 7;     // 0..7
  float rB[16];

  auto loadB = [&](int k0) {
#pragma unroll
    for (int h = 0; h < 2; ++h) {
      const float* p = W + (size_t)(k0 + kb + h * 32) * ND + n0 + co * 8;
      *reinterpret_cast<float4*>(&rB[h * 8])     = *reinterpret_cast<const float4*>(p);
      *reinterpret_cast<float4*>(&rB[h * 8 + 4]) = *reinterpret_cast<const float4*>(p + 4);
    }
  };
  auto writeB = [&](int buf) {
#pragma unroll
    for (int h = 0; h < 2; ++h) {
      const int k = kb + h * 32;
      short8 o;
#pragma unroll
      for (int j = 0; j < 8; ++j) o[j] = f2bf_hw(rB[h * 8 + j]);
      *reinterpret_cast<short8*>(
          (char*)&Bs[buf][0] + ((k >> 2) * 4 + (co >> 1)) * 128 + (k & 3) * 32 + (co & 1) * 16) = o;
    }
  };

  // ---- wave compute geometry ----
  const int wr  = (wid >> 1) * 64;
  const int wc  = (wid & 1) * 32;
  const int llo = lane & 15;
  const int lhi = lane >> 4;
  const int swz = (llo & 7) << 4;
  const unsigned c0 = (unsigned)((lhi * 16) ^ swz);
  const unsigned c1 = (unsigned)((64 + lhi * 16) ^ swz);
  const unsigned aAddr0 = lds_off(&As[0][0]) + (wr + llo) * 128;
  const unsigned bAddr0 = lds_off(&Bs[0][0]) + lhi * 1024 + (wc >> 4) * 128 + llo * 8;

  f32x4 acc[4][2];
#pragma unroll
  for (int i = 0; i < 4; ++i)
#pragma unroll
    for (int j = 0; j < 2; ++j) acc[i][j] = f32x4{0.f, 0.f, 0.f, 0.f};

  // prologue: fill buf 0
  if (MODE == 0) { loadA0(0); } else { loadA1(0, 0); }
  loadB(0);
  if (MODE == 0) writeA0(0);
  writeB(0);
  __syncthreads();

  for (int kt = 0; kt < 8; ++kt) {
    const int cb = kt & 1;
    const unsigned aOff = (unsigned)cb * 16384u;
    const unsigned bOff = (unsigned)cb * 8192u;
    if (kt < 7) {             // issue next-tile global loads early (T14)
      if (MODE == 0) { loadA0((kt + 1) * 64); } else { loadA1(cb ^ 1, (kt + 1) * 64); }
      loadB((kt + 1) * 64);
    }
#pragma unroll
    for (int kk = 0; kk < 2; ++kk) {
      const unsigned aA = aAddr0 + aOff + (kk ? c1 : c0);
      const unsigned bA = bAddr0 + bOff;
      short8 a0, a1, a2, a3;
      short4v t00, t01, t10, t11;
      DS128(a0, aA, 0);
      DS128(a1, aA, 2048);
      DS128(a2, aA, 4096);
      DS128(a3, aA, 6144);
      if (kk == 0) {
        TRB16(t00, bA, 0);    TRB16(t01, bA, 512);
        TRB16(t10, bA, 128);  TRB16(t11, bA, 640);
      } else {
        TRB16(t00, bA, 4096); TRB16(t01, bA, 4608);
        TRB16(t10, bA, 4224); TRB16(t11, bA, 4736);
      }
      asm volatile("s_waitcnt lgkmcnt(0)" ::: "memory");
      __builtin_amdgcn_sched_barrier(0);
      short8 b0 = __builtin_shufflevector(t00, t01, 0, 1, 2, 3, 4, 5, 6, 7);
      short8 b1 = __builtin_shufflevector(t10, t11, 0, 1, 2, 3, 4, 5, 6, 7);
      acc[0][0] = __builtin_amdgcn_mfma_f32_16x16x32_bf16(a0, b0, acc[0][0], 0, 0, 0);
      acc[0][1] = __builtin_amdgcn_mfma_f32_16x16x32_bf16(a0, b1, acc[0][1], 0, 0, 0);
      acc[1][0] = __builtin_amdgcn_mfma_f32_16x16x32_bf16(a1, b0, acc[1][0], 0, 0, 0);
      acc[1][1] = __builtin_amdgcn_mfma_f32_16x16x32_bf16(a1, b1, acc[1][1], 0, 0, 0);
      acc[2][0] = __builtin_amdgcn_mfma_f32_16x16x32_bf16(a2, b0, acc[2][0], 0, 0, 0);
      acc[2][1] = __builtin_amdgcn_mfma_f32_16x16x32_bf16(a2, b1, acc[2][1], 0, 0, 0);
      acc[3][0] = __builtin_amdgcn_mfma_f32_16x16x32_bf16(a3, b0, acc[3][0], 0, 0, 0);
      acc[3][1] = __builtin_amdgcn_mfma_f32_16x16x32_bf16(a3, b1, acc[3][1], 0, 0, 0);
    }
    if (kt < 7) {
      if (MODE == 0) writeA0(cb ^ 1);
      writeB(cb ^ 1);
      __syncthreads();
    }
  }

  // epilogue: bias + tanh + store
  float bj[2];
#pragma unroll
  for (int j = 0; j < 2; ++j) bj[j] = bias[n0 + wc + j * 16 + llo];

#pragma unroll
  for (int i = 0; i < 4; ++i) {
#pragma unroll
    for (int reg = 0; reg < 4; ++reg) {
      const int orow = wr + i * 16 + lhi * 4 + reg;
      if (row0 + orow < cnt) {
        if (MODE == 0) {
          size_t rb = (size_t)br * NB * ND + (size_t)(off + row0 + orow) * ND + n0;
#pragma unroll
          for (int j = 0; j < 2; ++j)
            Hc[rb + wc + j * 16 + llo] =
                (unsigned short)f2bf_hw(ftanh(acc[i][j][reg] + bj[j]));
        } else {
          const int tok = meta[TLIST + off + row0 + orow];
          size_t rb = (size_t)br * NB * ND + (size_t)tok * ND + n0;
#pragma unroll
          for (int j = 0; j < 2; ++j)
            out[rb + wc + j * 16 + llo] = ftanh(acc[i][j][reg] + bj[j]);
        }
      }
    }
  }
}

// ================= legacy fallback (round-2 proven, small ws) =================
constexpr int LTM = 64;
constexpr int LTN = 64;
constexpr int LBKT = 64;
constexpr int LBKP = LBKT + 8;
constexpr int LNT = ND / LTN;
constexpr int LMT_CAP = NB / LTM + NG;

template<int MODE>
__global__ __launch_bounds__(256, 4) void mlp_gemm(
    const float* __restrict__ X,
    __hip_bfloat16* __restrict__ Hp,
    __hip_bfloat16* __restrict__ Hv,
    const float* __restrict__ Wp, const float* __restrict__ bp,
    const float* __restrict__ Wv, const float* __restrict__ bv,
    const int* __restrict__ meta,
    float* __restrict__ out)
{
  const int tileIdx = blockIdx.y;
  if (tileIdx >= meta[NTILES]) return;
  const int g   = meta[TILEG + tileIdx];
  const int mt  = meta[TILEM + tileIdx];
  const int off = meta[OFFS + g];
  const int cnt = meta[OFFS + g + 1] - off;
  const int row0 = mt * LTM;
  const int n0 = blockIdx.x * LTN;
  const int br = blockIdx.z;

  const float* Wt   = (br ? Wv : Wp) + (size_t)g * DD;
  const float* bias = (br ? bv : bp) + (size_t)g * ND;

  __shared__ unsigned short As[2][LTM][LBKP];
  __shared__ unsigned short Bs[2][LTN][LBKP];

  const int t = threadIdx.x;
  const int r = t >> 2;
  const int q = t & 3;

  const int gr = row0 + r;
  const bool rowok = (gr < cnt);
  int tok = 0;
  if (MODE == 0) tok = rowok ? meta[TLIST + off + gr] : 0;
  const float* arow = X + (size_t)tok * ND;
  const __hip_bfloat16* Hin = br ? Hv : Hp;
  const unsigned short* hrow =
      (const unsigned short*)(Hin + (size_t)(off + (rowok ? gr : 0)) * ND);

  auto stage = [&](int buf, int k0) {
    if (MODE == 0) {
#pragma unroll
      for (int i = 0; i < 4; ++i) {
        int c = q * 16 + i * 4;
        float4 v = make_float4(0.f, 0.f, 0.f, 0.f);
        if (rowok) v = *reinterpret_cast<const float4*>(arow + k0 + c);
        ushort4 s;
        s.x = f2bf(v.x); s.y = f2bf(v.y); s.z = f2bf(v.z); s.w = f2bf(v.w);
        *reinterpret_cast<ushort4*>(&As[buf][r][c]) = s;
      }
    } else {
#pragma unroll
      for (int i = 0; i < 2; ++i) {
        int c = q * 16 + i * 8;
        int4 v = make_int4(0, 0, 0, 0);
        if (rowok) v = *reinterpret_cast<const int4*>(hrow + k0 + c);
        *reinterpret_cast<int4*>(&As[buf][r][c]) = v;
      }
    }
#pragma unroll
    for (int i = 0; i < 4; ++i) {
      int c = q * 16 + i * 4;
      float4 v = *reinterpret_cast<const float4*>(Wt + (size_t)(k0 + r) * ND + n0 + c);
      Bs[buf][c + 0][r] = f2bf(v.x);
      Bs[buf][c + 1][r] = f2bf(v.y);
      Bs[buf][c + 2][r] = f2bf(v.z);
      Bs[buf][c + 3][r] = f2bf(v.w);
    }
  };

  const int lane = t & 63;
  const int wid  = t >> 6;
  const int wr   = (wid >> 1) * 32;
  const int wc   = (wid & 1) * 32;
  const int lhi  = lane >> 4;
  const int llo  = lane & 15;

  f32x4 acc[2][2];
#pragma unroll
  for (int i = 0; i < 2; ++i)
#pragma unroll
    for (int j = 0; j < 2; ++j) acc[i][j] = f32x4{0.f, 0.f, 0.f, 0.f};

  stage(0, 0);
  __syncthreads();

  for (int kt = 0; kt < ND / LBKT; ++kt) {
    const int cb = kt & 1;
    if (kt + 1 < ND / LBKT) stage(cb ^ 1, (kt + 1) * LBKT);
#pragma unroll
    for (int kk = 0; kk < 2; ++kk) {
      int kbb = kk * 32 + lhi * 8;
      short8 a0 = *reinterpret_cast<const short8*>(&As[cb][wr + llo][kbb]);
      short8 a1 = *reinterpret_cast<const short8*>(&As[cb][wr + 16 + llo][kbb]);
      short8 b0 = *reinterpret_cast<const short8*>(&Bs[cb][wc + llo][kbb]);
      short8 b1 = *reinterpret_cast<const short8*>(&Bs[cb][wc + 16 + llo][kbb]);
      acc[0][0] = __builtin_amdgcn_mfma_f32_16x16x32_bf16(a0, b0, acc[0][0], 0, 0, 0);
      acc[0][1] = __builtin_amdgcn_mfma_f32_16x16x32_bf16(a0, b1, acc[0][1], 0, 0, 0);
      acc[1][0] = __builtin_amdgcn_mfma_f32_16x16x32_bf16(a1, b0, acc[1][0], 0, 0, 0);
      acc[1][1] = __builtin_amdgcn_mfma_f32_16x16x32_bf16(a1, b1, acc[1][1], 0, 0, 0);
    }
    __syncthreads();
  }

  float bj0 = bias[n0 + wc + llo];
  float bj1 = bias[n0 + wc + 16 + llo];
  __hip_bfloat16* Hout = br ? Hv : Hp;
#pragma unroll
  for (int i = 0; i < 2; ++i) {
#pragma unroll
    for (int reg = 0; reg < 4; ++reg) {
      int m = wr + i * 16 + lhi * 4 + reg;
      int grr = row0 + m;
      if (grr < cnt) {
        float v0 = ftanh(acc[i][0][reg] + bj0);
        float v1 = ftanh(acc[i][1][reg] + bj1);
        if (MODE == 0) {
          size_t rowbase = (size_t)(off + grr) * ND + n0;
          Hout[rowbase + wc + llo]      = __float2bfloat16(v0);
          Hout[rowbase + wc + 16 + llo] = __float2bfloat16(v1);
        } else {
          int tok2 = meta[TLIST + off + grr];
          size_t rowbase = (size_t)br * NB * ND + (size_t)tok2 * ND + n0;
          out[rowbase + wc + llo]      = v0;
          out[rowbase + wc + 16 + llo] = v1;
        }
      }
    }
  }
}

extern "C" void kernel_launch(void* const* d_in, const int* in_sizes, int n_in,
                              void* d_out, int out_size, void* d_ws, size_t ws_size,
                              hipStream_t stream) {
  const float* features = (const float*)d_in[0];
  const float* Wp0 = (const float*)d_in[1];
  const float* bp0 = (const float*)d_in[2];
  const float* Wp1 = (const float*)d_in[3];
  const float* bp1 = (const float*)d_in[4];
  const float* Wv0 = (const float*)d_in[5];
  const float* bv0 = (const float*)d_in[6];
  const float* Wv1 = (const float*)d_in[7];
  const float* bv1 = (const float*)d_in[8];
  const int* goal  = (const int*)d_in[9];
  float* out = (float*)d_out;
  int* meta = (int*)d_ws;

  if (ws_size >= FAST_WS_NEED) {
    unsigned short* Hc = (unsigned short*)((char*)d_ws + HC_OFF);

    bin_k<<<1, 1024, 0, stream>>>(goal, meta, 128);

    dim3 grid(ND / 64, NB / 128 + NG, 2);
    gemm_t<0><<<grid, 256, 0, stream>>>(features, Hc, Wp0, Wv0, bp0, bv0, meta, out);
    gemm_t<1><<<grid, 256, 0, stream>>>(features, Hc, Wp1, Wv1, bp1, bv1, meta, out);
  } else {
    __hip_bfloat16* Hp = (__hip_bfloat16*)((char*)d_ws + H_OFF);
    __hip_bfloat16* Hv = Hp + (size_t)NB * ND;

    bin_k<<<1, 1024, 0, stream>>>(goal, meta, LTM);
    dim3 grid(LNT, LMT_CAP, 2);
    mlp_gemm<0><<<grid, 256, 0, stream>>>(features, Hp, Hv, Wp0, bp0, Wv0, bv0, meta, out);
    mlp_gemm<1><<<grid, 256, 0, stream>>>(features, Hp, Hv, Wp1, bp1, Wv1, bv1, meta, out);
  }
}